// Round 4
// baseline (576.882 us; speedup 1.0000x reference)
//
#include <hip/hip_runtime.h>

// Problem constants
#define N_NODES   300000
#define K_STENCIL 27
#define CIN       32
#define COUT      64
#define BN_EPS    1e-5f

// Workspace layout (bytes):
//   [0, 32768)           : split stats, 64 splits x (sum[64], sumsq[64]) fp32
//   [32768, 33280)       : ab coeffs a[64], b[64] fp32
//   [33280, 143872)      : weightT bf16 [27][64][32]
#define WS_STATS_OFF 0
#define WS_AB_OFF    32768
#define WS_WT_OFF    33280
#define N_SPLITS     64

typedef short bf16x8 __attribute__((ext_vector_type(8)));
typedef float f32x4  __attribute__((ext_vector_type(4)));

__device__ __forceinline__ short f2bf_rne(float f) {
    unsigned u = __builtin_bit_cast(unsigned, f);
    u += 0x7fffu + ((u >> 16) & 1u);   // round-to-nearest-even
    return (short)(u >> 16);
}

// ---------------------------------------------------------------------------
// prep: zero split-stats (8192 floats) + weight [27][32][64] fp32 ->
// weightT [27][64][32] bf16. 55296 weight elems; 217 blocks x 256.
// ---------------------------------------------------------------------------
__global__ __launch_bounds__(256) void prep(const float* __restrict__ w,
                                            unsigned short* __restrict__ wT,
                                            float* __restrict__ stats) {
    int t = blockIdx.x * blockDim.x + threadIdx.x;
    if (t < N_SPLITS * 128) stats[t] = 0.f;
    if (t < K_STENCIL * COUT * CIN) {
        int c = t & (CIN - 1);
        int o = (t >> 5) & (COUT - 1);
        int k = t >> 11;
        wT[t] = (unsigned short)f2bf_rne(w[(k * CIN + c) * COUT + o]);
    }
}

// ---------------------------------------------------------------------------
// Gather-GEMM via MFMA — EXACT R0 inner structure (the 255 us / 2.34 TB/s
// schedule): 3 groups of 9 stencil taps; per group, issue all 9 neigh-index
// loads, then all 18 gather dwordx4 loads into live register arrays, then
// drain through converts + 36 MFMAs. The fp32 lo/hi + f2bf convert chain is
// what keeps the compiler holding ~8 gather loads in flight (VGPR=64); the
// bf16-table variants (R1/R3) that load MFMA operands directly collapse to
// ~2.4 in flight and run 1.6x slower — do NOT "simplify" this loop.
// New vs R0: BN split-stats fused into the epilogue (post-loop, schedule-
// neutral; kills the separate 76.8 MB stats_pass sweep).
// ---------------------------------------------------------------------------
__global__ __launch_bounds__(256, 2) void conv_mfma(
        const float* __restrict__ data, const int* __restrict__ neigh,
        const unsigned short* __restrict__ wT, float* __restrict__ out,
        float* __restrict__ stats) {
    const int wave  = threadIdx.x >> 6;
    const int lane  = threadIdx.x & 63;
    const int row16 = lane & 15;
    const int quad  = lane >> 4;

    __shared__ float lsum[COUT];
    __shared__ float lsq[COUT];
    if (threadIdx.x < COUT) { lsum[threadIdx.x] = 0.f; lsq[threadIdx.x] = 0.f; }

    // ---- layout probe: D = I*T, T[k][n]=k*16+n -> slot value encodes (m,n)
    bf16x8 ia, tb;
    #pragma unroll
    for (int j = 0; j < 8; ++j) {
        int k = quad * 8 + j;
        ia[j] = (k == row16) ? (short)0x3F80 : (short)0;
        tb[j] = f2bf_rne((float)(k * 16 + row16));
    }
    f32x4 pacc = {0.f, 0.f, 0.f, 0.f};
    pacc = __builtin_amdgcn_mfma_f32_16x16x32_bf16(ia, tb, pacc, 0, 0, 0);
    int mrow[4], ncol[4];
    #pragma unroll
    for (int r = 0; r < 4; ++r) {
        int iv = (int)(pacc[r] + 0.5f);
        mrow[r] = (iv >> 4) & 15;
        ncol[r] = iv & 15;
    }

    // ---- main gather-GEMM (R0-proven) ----
    const int node   = blockIdx.x * 64 + wave * 16 + row16;
    const bool valid = (node < N_NODES);
    const int nclamp = valid ? node : 0;

    f32x4 acc[4] = {f32x4{0,0,0,0}, f32x4{0,0,0,0}, f32x4{0,0,0,0}, f32x4{0,0,0,0}};
    const int* nrow = neigh + nclamp * K_STENCIL;

    #pragma unroll
    for (int g = 0; g < 3; ++g) {
        // 1) neighbor indices for this group
        int kid[9];
        #pragma unroll
        for (int j = 0; j < 9; ++j) kid[j] = nrow[g * 9 + j];

        // 2) issue all gathers (2x f32x4 per tap) into live arrays
        f32x4 lo[9], hi[9];
        #pragma unroll
        for (int j = 0; j < 9; ++j) {
            int idx = kid[j];
            if (valid && idx >= 0) {
                const f32x4* drow = (const f32x4*)(data + (size_t)idx * CIN + quad * 8);
                lo[j] = drow[0];
                hi[j] = drow[1];
            } else {
                lo[j] = f32x4{0, 0, 0, 0};
                hi[j] = f32x4{0, 0, 0, 0};
            }
        }

        // 3) drain: pack bf16 + 4 MFMAs per tap
        #pragma unroll
        for (int j = 0; j < 9; ++j) {
            bf16x8 afrag;
            #pragma unroll
            for (int t = 0; t < 4; ++t) {
                afrag[t]     = f2bf_rne(lo[j][t]);
                afrag[t + 4] = f2bf_rne(hi[j][t]);
            }
            const unsigned short* wk = wT + (g * 9 + j) * (COUT * CIN) + row16 * CIN + quad * 8;
            #pragma unroll
            for (int ct = 0; ct < 4; ++ct) {
                bf16x8 bfrag = *(const bf16x8*)(wk + ct * 16 * CIN);
                acc[ct] = __builtin_amdgcn_mfma_f32_16x16x32_bf16(afrag, bfrag, acc[ct], 0, 0, 0);
            }
        }
    }

    // ---- epilogue: write out + fused BN split-stats ----
    __syncthreads();   // lsum/lsq init visible before atomics
    const int tilebase = blockIdx.x * 64 + wave * 16;
    #pragma unroll
    for (int ct = 0; ct < 4; ++ct) {
        #pragma unroll
        for (int r = 0; r < 4; ++r) {
            int n_out = tilebase + mrow[r];
            int col   = ct * 16 + ncol[r];
            float v   = acc[ct][r];          // invalid rows: exact 0.0
            if (n_out < N_NODES)
                out[(size_t)n_out * COUT + col] = v;
            atomicAdd(&lsum[col], v);
            atomicAdd(&lsq[col], v * v);
        }
    }
    __syncthreads();
    if (threadIdx.x < 128) {
        int split = blockIdx.x & (N_SPLITS - 1);
        float v = (threadIdx.x < 64) ? lsum[threadIdx.x] : lsq[threadIdx.x - 64];
        atomicAdd(&stats[split * 128 + threadIdx.x], v);
    }
}

// ---------------------------------------------------------------------------
__global__ void finalize_stats(const float* __restrict__ stats,
                               const float* __restrict__ gamma,
                               const float* __restrict__ beta,
                               float* __restrict__ ab) {
    int o = threadIdx.x;  // 64 threads
    if (o >= COUT) return;
    float s = 0.f, q = 0.f;
    for (int sp = 0; sp < N_SPLITS; ++sp) {
        s += stats[sp * 128 + o];
        q += stats[sp * 128 + 64 + o];
    }
    float inv_n = 1.0f / (float)N_NODES;
    float mean = s * inv_n;
    float var  = q * inv_n - mean * mean;
    float a = gamma[o] * rsqrtf(var + BN_EPS);
    float b = beta[o] - mean * a;
    ab[o] = a;
    ab[64 + o] = b;
}

// ---------------------------------------------------------------------------
__global__ __launch_bounds__(256) void bn_relu(float* __restrict__ out,
                                               const float* __restrict__ ab) {
    int i = blockIdx.x * blockDim.x + threadIdx.x;  // float4 index, exact grid
    f32x4 a = ((const f32x4*)ab)[i & 15];
    f32x4 b = ((const f32x4*)(ab + 64))[i & 15];
    f32x4 v = ((f32x4*)out)[i];
    #pragma unroll
    for (int j = 0; j < 4; ++j) {
        float y = v[j] * a[j] + b[j];
        v[j] = y > 0.f ? y : 0.f;
    }
    ((f32x4*)out)[i] = v;
}

// ---------------------------------------------------------------------------
extern "C" void kernel_launch(void* const* d_in, const int* in_sizes, int n_in,
                              void* d_out, int out_size, void* d_ws, size_t ws_size,
                              hipStream_t stream) {
    const float* data   = (const float*)d_in[0];
    const int*   neigh  = (const int*)d_in[1];     // int32 on device
    const float* weight = (const float*)d_in[2];
    const float* gamma  = (const float*)d_in[3];
    const float* beta   = (const float*)d_in[4];
    float* out = (float*)d_out;

    char* ws = (char*)d_ws;
    float*          stats = (float*)(ws + WS_STATS_OFF);
    float*          ab    = (float*)(ws + WS_AB_OFF);
    unsigned short* wT    = (unsigned short*)(ws + WS_WT_OFF);

    prep<<<(K_STENCIL * COUT * CIN + 255) / 256, 256, 0, stream>>>(weight, wT, stats);

    const int grid = (N_NODES + 63) / 64;  // 4688
    conv_mfma<<<grid, 256, 0, stream>>>(data, neigh, wT, out, stats);

    finalize_stats<<<1, 64, 0, stream>>>(stats, gamma, beta, ab);

    int total4 = N_NODES * COUT / 4;  // 4,800,000
    bn_relu<<<total4 / 256, 256, 0, stream>>>(out, ab);
}

// Round 5
// 405.867 us; speedup vs baseline: 1.4214x; 1.4214x over previous
//
#include <hip/hip_runtime.h>

// Problem constants
#define N_NODES   300000
#define K_STENCIL 27
#define CIN       32
#define COUT      64
#define BN_EPS    1e-5f

// Workspace layout (bytes):
//   [0, 32768)           : split stats, 64 splits x (sum[64], sumsq[64]) fp32
//   [32768, 33280)       : ab coeffs a[64], b[64] fp32
//   [33280, 33344)       : done-counter (uint) + pad
//   [33792, 144384)      : weightT bf16 [27][64][32]
#define WS_STATS_OFF 0
#define WS_AB_OFF    32768
#define WS_CNT_OFF   33280
#define WS_WT_OFF    33792
#define N_SPLITS     64

typedef short bf16x8 __attribute__((ext_vector_type(8)));
typedef float f32x4  __attribute__((ext_vector_type(4)));

__device__ __forceinline__ short f2bf_rne(float f) {
    unsigned u = __builtin_bit_cast(unsigned, f);
    u += 0x7fffu + ((u >> 16) & 1u);   // round-to-nearest-even
    return (short)(u >> 16);
}

// ---------------------------------------------------------------------------
// prep: zero split-stats (8192 floats) + done-counter + weight [27][32][64]
// fp32 -> weightT [27][64][32] bf16. 55296 weight elems; 217 blocks x 256.
// ---------------------------------------------------------------------------
__global__ __launch_bounds__(256) void prep(const float* __restrict__ w,
                                            unsigned short* __restrict__ wT,
                                            float* __restrict__ stats,
                                            unsigned int* __restrict__ cnt) {
    int t = blockIdx.x * blockDim.x + threadIdx.x;
    if (t < N_SPLITS * 128) stats[t] = 0.f;
    if (t == 0) *cnt = 0u;
    if (t < K_STENCIL * COUT * CIN) {
        int c = t & (CIN - 1);
        int o = (t >> 5) & (COUT - 1);
        int k = t >> 11;
        wT[t] = (unsigned short)f2bf_rne(w[(k * CIN + c) * COUT + o]);
    }
}

// ---------------------------------------------------------------------------
// Gather-GEMM via MFMA — EXACT R0 kernel, byte-for-byte. FROZEN.
// R1/R3/R4 evidence: ANY change to this kernel's body (bf16-table operand
// loads, sched_barrier pinning, or even a post-loop LDS/atomic epilogue)
// makes the RA register-minimize the lo/hi live arrays (VGPR 64->56/80),
// collapsing the gather pipeline from ~8 in-flight to ~2.4 and the request
// rate by 1.6-3.3x. The fp32 lo/hi arrays + f2bf convert chain feeding the
// MFMAs is precisely the shape the scheduler pipelines well. DO NOT TOUCH.
// ---------------------------------------------------------------------------
__global__ __launch_bounds__(256, 2) void conv_mfma(
        const float* __restrict__ data, const int* __restrict__ neigh,
        const unsigned short* __restrict__ wT, float* __restrict__ out) {
    const int wave  = threadIdx.x >> 6;
    const int lane  = threadIdx.x & 63;
    const int row16 = lane & 15;
    const int quad  = lane >> 4;

    // ---- layout probe: D = I*T, T[k][n]=k*16+n -> slot value encodes (m,n)
    bf16x8 ia, tb;
    #pragma unroll
    for (int j = 0; j < 8; ++j) {
        int k = quad * 8 + j;
        ia[j] = (k == row16) ? (short)0x3F80 : (short)0;
        tb[j] = f2bf_rne((float)(k * 16 + row16));
    }
    f32x4 pacc = {0.f, 0.f, 0.f, 0.f};
    pacc = __builtin_amdgcn_mfma_f32_16x16x32_bf16(ia, tb, pacc, 0, 0, 0);
    int mrow[4], ncol[4];
    #pragma unroll
    for (int r = 0; r < 4; ++r) {
        int iv = (int)(pacc[r] + 0.5f);
        mrow[r] = (iv >> 4) & 15;
        ncol[r] = iv & 15;
    }

    // ---- main gather-GEMM ----
    const int node   = blockIdx.x * 64 + wave * 16 + row16;
    const bool valid = (node < N_NODES);
    const int nclamp = valid ? node : 0;

    f32x4 acc[4] = {f32x4{0,0,0,0}, f32x4{0,0,0,0}, f32x4{0,0,0,0}, f32x4{0,0,0,0}};
    const int* nrow = neigh + nclamp * K_STENCIL;

    #pragma unroll
    for (int g = 0; g < 3; ++g) {
        // 1) neighbor indices for this group
        int kid[9];
        #pragma unroll
        for (int j = 0; j < 9; ++j) kid[j] = nrow[g * 9 + j];

        // 2) issue all gathers (2x f32x4 per tap) into live register arrays
        f32x4 lo[9], hi[9];
        #pragma unroll
        for (int j = 0; j < 9; ++j) {
            int idx = kid[j];
            if (valid && idx >= 0) {
                const f32x4* drow = (const f32x4*)(data + (size_t)idx * CIN + quad * 8);
                lo[j] = drow[0];
                hi[j] = drow[1];
            } else {
                lo[j] = f32x4{0, 0, 0, 0};
                hi[j] = f32x4{0, 0, 0, 0};
            }
        }

        // 3) drain: pack bf16 + 4 MFMAs per tap
        #pragma unroll
        for (int j = 0; j < 9; ++j) {
            bf16x8 afrag;
            #pragma unroll
            for (int t = 0; t < 4; ++t) {
                afrag[t]     = f2bf_rne(lo[j][t]);
                afrag[t + 4] = f2bf_rne(hi[j][t]);
            }
            const unsigned short* wk = wT + (g * 9 + j) * (COUT * CIN) + row16 * CIN + quad * 8;
            #pragma unroll
            for (int ct = 0; ct < 4; ++ct) {
                bf16x8 bfrag = *(const bf16x8*)(wk + ct * 16 * CIN);
                acc[ct] = __builtin_amdgcn_mfma_f32_16x16x32_bf16(afrag, bfrag, acc[ct], 0, 0, 0);
            }
        }
    }

    // ---- epilogue with discovered (m,n) mapping ----
    const int tilebase = blockIdx.x * 64 + wave * 16;
    #pragma unroll
    for (int ct = 0; ct < 4; ++ct) {
        #pragma unroll
        for (int r = 0; r < 4; ++r) {
            int n_out = tilebase + mrow[r];
            if (n_out < N_NODES)
                out[(size_t)n_out * COUT + ct * 16 + ncol[r]] = acc[ct][r];
        }
    }
}

// ---------------------------------------------------------------------------
// BN stats over out[N][64] (R0 stats_pass) + last-block finalize fused in.
// Last-block pattern is dispatch-order-safe: no spinning, no residency
// assumption. Writers: split atomicAdds then __threadfence then counter
// increment (release). The single block observing count==grid-1 reads the
// splits with device-scope atomic loads (acquire) — safe across XCD L2s.
// ---------------------------------------------------------------------------
__global__ __launch_bounds__(256) void stats_fin(const float* __restrict__ out,
                                                 float* __restrict__ stats,
                                                 unsigned int* __restrict__ cnt,
                                                 const float* __restrict__ gamma,
                                                 const float* __restrict__ beta,
                                                 float* __restrict__ ab) {
    __shared__ float lsum[COUT];
    __shared__ float lsq[COUT];
    __shared__ int lastFlag;
    if (threadIdx.x < COUT) { lsum[threadIdx.x] = 0.f; lsq[threadIdx.x] = 0.f; }
    __syncthreads();

    const int j = threadIdx.x & 15;
    int row = blockIdx.x * 16 + (threadIdx.x >> 4);
    const int rstride = gridDim.x * 16;
    float s0=0,s1=0,s2=0,s3=0,q0=0,q1=0,q2=0,q3=0;
    for (; row < N_NODES; row += rstride) {
        f32x4 v = ((const f32x4*)out)[row * 16 + j];
        s0 += v[0]; q0 += v[0]*v[0];
        s1 += v[1]; q1 += v[1]*v[1];
        s2 += v[2]; q2 += v[2]*v[2];
        s3 += v[3]; q3 += v[3]*v[3];
    }
    atomicAdd(&lsum[j*4+0], s0); atomicAdd(&lsq[j*4+0], q0);
    atomicAdd(&lsum[j*4+1], s1); atomicAdd(&lsq[j*4+1], q1);
    atomicAdd(&lsum[j*4+2], s2); atomicAdd(&lsq[j*4+2], q2);
    atomicAdd(&lsum[j*4+3], s3); atomicAdd(&lsq[j*4+3], q3);
    __syncthreads();

    if (threadIdx.x < 128) {
        int split = blockIdx.x & (N_SPLITS - 1);
        float v = (threadIdx.x < 64) ? lsum[threadIdx.x] : lsq[threadIdx.x - 64];
        atomicAdd(&stats[split * 128 + threadIdx.x], v);
    }
    __syncthreads();

    if (threadIdx.x == 0) {
        __threadfence();                       // release our split atomics
        unsigned old = atomicAdd(cnt, 1u);
        lastFlag = (old == gridDim.x - 1) ? 1 : 0;
    }
    __syncthreads();

    if (lastFlag && threadIdx.x < COUT) {
        int o = threadIdx.x;
        float s = 0.f, q = 0.f;
        for (int sp = 0; sp < N_SPLITS; ++sp) {
            s += __hip_atomic_load(&stats[sp * 128 + o],
                                   __ATOMIC_RELAXED, __HIP_MEMORY_SCOPE_AGENT);
            q += __hip_atomic_load(&stats[sp * 128 + 64 + o],
                                   __ATOMIC_RELAXED, __HIP_MEMORY_SCOPE_AGENT);
        }
        float inv_n = 1.0f / (float)N_NODES;
        float mean = s * inv_n;
        float var  = q * inv_n - mean * mean;
        float a = gamma[o] * rsqrtf(var + BN_EPS);
        float b = beta[o] - mean * a;
        ab[o] = a;          // kernel boundary flushes before bn_relu reads
        ab[64 + o] = b;
    }
}

// ---------------------------------------------------------------------------
__global__ __launch_bounds__(256) void bn_relu(float* __restrict__ out,
                                               const float* __restrict__ ab) {
    int i = blockIdx.x * blockDim.x + threadIdx.x;  // float4 index, exact grid
    f32x4 a = ((const f32x4*)ab)[i & 15];
    f32x4 b = ((const f32x4*)(ab + 64))[i & 15];
    f32x4 v = ((f32x4*)out)[i];
    #pragma unroll
    for (int j = 0; j < 4; ++j) {
        float y = v[j] * a[j] + b[j];
        v[j] = y > 0.f ? y : 0.f;
    }
    ((f32x4*)out)[i] = v;
}

// ---------------------------------------------------------------------------
extern "C" void kernel_launch(void* const* d_in, const int* in_sizes, int n_in,
                              void* d_out, int out_size, void* d_ws, size_t ws_size,
                              hipStream_t stream) {
    const float* data   = (const float*)d_in[0];
    const int*   neigh  = (const int*)d_in[1];     // int32 on device
    const float* weight = (const float*)d_in[2];
    const float* gamma  = (const float*)d_in[3];
    const float* beta   = (const float*)d_in[4];
    float* out = (float*)d_out;

    char* ws = (char*)d_ws;
    float*          stats = (float*)(ws + WS_STATS_OFF);
    float*          ab    = (float*)(ws + WS_AB_OFF);
    unsigned int*   cnt   = (unsigned int*)(ws + WS_CNT_OFF);
    unsigned short* wT    = (unsigned short*)(ws + WS_WT_OFF);

    prep<<<(K_STENCIL * COUT * CIN + 255) / 256, 256, 0, stream>>>(weight, wT, stats, cnt);

    const int grid = (N_NODES + 63) / 64;  // 4688
    conv_mfma<<<grid, 256, 0, stream>>>(data, neigh, wT, out);

    stats_fin<<<1024, 256, 0, stream>>>(out, stats, cnt, gamma, beta, ab);

    int total4 = N_NODES * COUT / 4;  // 4,800,000
    bn_relu<<<total4 / 256, 256, 0, stream>>>(out, ab);
}